// Round 3
// baseline (300.823 us; speedup 1.0000x reference)
//
#include <hip/hip_runtime.h>
#include <math.h>

#define BN_EPS 0.001f
#define GEMM_BM 64
#define BUCK_CAP 2048

__device__ inline unsigned bf16rne(float f) {
  unsigned u = __float_as_uint(f);
  return (u + 0x7fffu + ((u >> 16) & 1u)) >> 16;
}
__device__ inline float bflo(unsigned r) { return __uint_as_float(r << 16); }
__device__ inline float bfhi(unsigned r) { return __uint_as_float(r & 0xffff0000u); }

// ---------------- phase A: bin edges by src>>6, packed u32 records ----------------
// record: bits[16:0] = dst (n < 131072), bits[22:17] = src & 63
__global__ void k_bin(const int4* __restrict__ ep2, int ne,
                      int* __restrict__ bcnt, unsigned* __restrict__ bins) {
  int h = blockIdx.x * blockDim.x + threadIdx.x;
  int e = 2 * h;
  if (e < ne) {
    int4 p = ep2[h];
    {
      int bk = p.x >> 6;
      int slot = atomicAdd(&bcnt[bk], 1);
      if (slot < BUCK_CAP)
        bins[(size_t)bk * BUCK_CAP + slot] =
            (unsigned)p.y | ((unsigned)(p.x & 63) << 17);
    }
    if (e + 1 < ne) {
      int bk = p.z >> 6;
      int slot = atomicAdd(&bcnt[bk], 1);
      if (slot < BUCK_CAP)
        bins[(size_t)bk * BUCK_CAP + slot] =
            (unsigned)p.w | ((unsigned)(p.z & 63) << 17);
    }
  }
}

// ---------------- phase B1: per-bucket LDS histogram -> deg ----------------
__global__ __launch_bounds__(256) void k_bcount(const int* __restrict__ bcnt,
                                                const unsigned* __restrict__ bins,
                                                int n, int* __restrict__ deg) {
  __shared__ int h[64];
  int bk = blockIdx.x;
  int t = threadIdx.x;
  if (t < 64) h[t] = 0;
  __syncthreads();
  int cnt = min(bcnt[bk], BUCK_CAP);
  const unsigned* bp = bins + (size_t)bk * BUCK_CAP;
  for (int idx = t; idx < cnt; idx += 256) atomicAdd(&h[bp[idx] >> 17], 1);
  __syncthreads();
  if (t < 64) {
    int node = (bk << 6) + t;
    if (node < n) deg[node] = h[t];
  }
}

// ---------------- scan step 1: per-256-block sums ----------------
__global__ void k_blocksum(const int* __restrict__ deg, int n, int* __restrict__ bsum) {
  __shared__ int sdata[256];
  int t = threadIdx.x;
  int i = blockIdx.x * 256 + t;
  sdata[t] = (i < n) ? deg[i] : 0;
  __syncthreads();
  for (int s = 128; s > 0; s >>= 1) {
    if (t < s) sdata[t] += sdata[t + s];
    __syncthreads();
  }
  if (t == 0) bsum[blockIdx.x] = sdata[0];
}

// ---------------- scan step 2: single-block scan of block sums (nb <= 256) ----------------
__global__ void k_scan_bsums(const int* __restrict__ bsum, int nb, int* __restrict__ boff) {
  __shared__ int s0[256], s1[256];
  int t = threadIdx.x;
  int v = (t < nb) ? bsum[t] : 0;
  s0[t] = v;
  __syncthreads();
  int* src = s0; int* dst = s1;
  for (int off = 1; off < 256; off <<= 1) {
    int x = src[t];
    if (t >= off) x += src[t - off];
    dst[t] = x;
    __syncthreads();
    int* tmp = src; src = dst; dst = tmp;
  }
  if (t < nb) boff[t] = src[t] - v;  // exclusive
}

// ---------------- scan step 3: per-block exclusive scan + isd ----------------
__global__ void k_scan_final(const int* __restrict__ deg, int n, const int* __restrict__ boff,
                             int* __restrict__ offsets, float* __restrict__ isd) {
  __shared__ int s0[256], s1[256];
  int t = threadIdx.x;
  int i = blockIdx.x * 256 + t;
  int v = (i < n) ? deg[i] : 0;
  s0[t] = v;
  __syncthreads();
  int* src = s0; int* dst = s1;
  for (int off = 1; off < 256; off <<= 1) {
    int x = src[t];
    if (t >= off) x += src[t - off];
    dst[t] = x;
    __syncthreads();
    int* tmp = src; src = dst; dst = tmp;
  }
  if (i < n) {
    offsets[i] = src[t] - v + boff[blockIdx.x];
    isd[i] = 1.0f / sqrtf((float)deg[i]);  // deg==0 -> +inf, matches jnp.power
  }
}

// ---------------- phase B2: per-bucket CSR fill with LDS cursors ----------------
__global__ __launch_bounds__(256) void k_bfill(const int* __restrict__ bcnt,
                                               const unsigned* __restrict__ bins,
                                               const int* __restrict__ offsets, int n,
                                               int* __restrict__ csr_dst) {
  __shared__ int cur[64];
  int bk = blockIdx.x;
  int t = threadIdx.x;
  if (t < 64) {
    int node = (bk << 6) + t;
    cur[t] = (node < n) ? offsets[node] : 0;
  }
  __syncthreads();
  int cnt = min(bcnt[bk], BUCK_CAP);
  const unsigned* bp = bins + (size_t)bk * BUCK_CAP;
  for (int idx = t; idx < cnt; idx += 256) {
    unsigned r = bp[idx];
    int pos = atomicAdd(&cur[r >> 17], 1);
    csr_dst[pos] = (int)(r & 0x1FFFFu);
  }
}

// ---------------- fp32 GEMM: T = X @ W + b, also emits bf16-packed Tb ----------------
__global__ __launch_bounds__(256) void k_gemm(const float* __restrict__ X,
                                              const float* __restrict__ W,
                                              const float* __restrict__ b,
                                              float* __restrict__ T,
                                              unsigned* __restrict__ Tb, int M) {
  constexpr int LDA = 68;
  constexpr int LDW = 132;
  __shared__ float As[64 * LDA];
  __shared__ float Ws[64 * LDW];
  int tid = threadIdx.x;
  int brow = blockIdx.x * GEMM_BM;
  int rows_here = M - brow;
  if (rows_here > GEMM_BM) rows_here = GEMM_BM;
  int tx = tid & 15;   // cols tx*8 .. +7
  int ty = tid >> 4;   // rows ty*4 .. +3
  float acc[4][8] = {};
  for (int kt = 0; kt < 2; ++kt) {
    __syncthreads();
    for (int idx = tid; idx < 64 * 32; idx += 256) {
      int k = idx >> 5;
      int c4 = idx & 31;
      float4 v = ((const float4*)(W + ((kt * 64 + k) << 7)))[c4];
      *(float4*)&Ws[k * LDW + c4 * 4] = v;
    }
    for (int idx = tid; idx < 64 * 16; idx += 256) {
      int r = idx >> 4;
      int kq = idx & 15;
      float4 v = make_float4(0.f, 0.f, 0.f, 0.f);
      if (r < rows_here)
        v = ((const float4*)(X + (((size_t)(brow + r)) << 7) + kt * 64))[kq];
      As[(kq * 4 + 0) * LDA + r] = v.x;
      As[(kq * 4 + 1) * LDA + r] = v.y;
      As[(kq * 4 + 2) * LDA + r] = v.z;
      As[(kq * 4 + 3) * LDA + r] = v.w;
    }
    __syncthreads();
#pragma unroll 8
    for (int k = 0; k < 64; ++k) {
      float4 av = *(const float4*)&As[k * LDA + ty * 4];
      float4 w0 = *(const float4*)&Ws[k * LDW + tx * 8];
      float4 w1 = *(const float4*)&Ws[k * LDW + tx * 8 + 4];
      float a[4] = {av.x, av.y, av.z, av.w};
      float w[8] = {w0.x, w0.y, w0.z, w0.w, w1.x, w1.y, w1.z, w1.w};
#pragma unroll
      for (int r = 0; r < 4; ++r)
#pragma unroll
        for (int c = 0; c < 8; ++c)
          acc[r][c] = fmaf(a[r], w[c], acc[r][c]);
    }
  }
  float4 b0 = ((const float4*)b)[tx * 2];
  float4 b1 = ((const float4*)b)[tx * 2 + 1];
  float bias[8] = {b0.x, b0.y, b0.z, b0.w, b1.x, b1.y, b1.z, b1.w};
  for (int r = 0; r < 4; ++r) {
    int row = brow + ty * 4 + r;
    if (row < M) {
      float o[8];
#pragma unroll
      for (int c = 0; c < 8; ++c) o[c] = acc[r][c] + bias[c];
      float* dst = T + (((size_t)row) << 7) + tx * 8;
      *(float4*)dst = make_float4(o[0], o[1], o[2], o[3]);
      *(float4*)(dst + 4) = make_float4(o[4], o[5], o[6], o[7]);
      unsigned pk[4];
#pragma unroll
      for (int c = 0; c < 4; ++c)
        pk[c] = bf16rne(o[2 * c]) | (bf16rne(o[2 * c + 1]) << 16);
      *(uint4*)(Tb + (((size_t)row) << 6) + tx * 4) =
          make_uint4(pk[0], pk[1], pk[2], pk[3]);
    }
  }
}

// ---------------- gather: one wave per node, bf16 neighbor rows ----------------
__global__ __launch_bounds__(256) void k_gather(
    const float* __restrict__ T, const unsigned* __restrict__ Tb,
    const int* __restrict__ deg, const float* __restrict__ isd,
    const int* __restrict__ offsets, const int* __restrict__ csr_dst,
    const float* __restrict__ mm, const float* __restrict__ var,
    const float* __restrict__ gamma, const float* __restrict__ beta,
    float* __restrict__ out, int n) {
  int wave = threadIdx.x >> 6;
  int lane = threadIdx.x & 63;
  int i = blockIdx.x * 4 + wave;
  if (i >= n) return;
  int degi = deg[i];
  int start = offsets[i];
  float sx0 = 0.f, sy0 = 0.f, sx1 = 0.f, sy1 = 0.f;
  float sx2 = 0.f, sy2 = 0.f, sx3 = 0.f, sy3 = 0.f;
  int e = 0;
  for (; e + 4 <= degi; e += 4) {
    int d0 = csr_dst[start + e];
    int d1 = csr_dst[start + e + 1];
    int d2 = csr_dst[start + e + 2];
    int d3 = csr_dst[start + e + 3];
    unsigned r0 = Tb[((size_t)d0 << 6) + lane];
    unsigned r1 = Tb[((size_t)d1 << 6) + lane];
    unsigned r2 = Tb[((size_t)d2 << 6) + lane];
    unsigned r3 = Tb[((size_t)d3 << 6) + lane];
    float is0 = isd[d0], is1 = isd[d1], is2 = isd[d2], is3 = isd[d3];
    sx0 = fmaf(bflo(r0), is0, sx0); sy0 = fmaf(bfhi(r0), is0, sy0);
    sx1 = fmaf(bflo(r1), is1, sx1); sy1 = fmaf(bfhi(r1), is1, sy1);
    sx2 = fmaf(bflo(r2), is2, sx2); sy2 = fmaf(bfhi(r2), is2, sy2);
    sx3 = fmaf(bflo(r3), is3, sx3); sy3 = fmaf(bfhi(r3), is3, sy3);
  }
  for (; e < degi; ++e) {
    int d = csr_dst[start + e];
    unsigned r = Tb[((size_t)d << 6) + lane];
    float is = isd[d];
    sx0 = fmaf(bflo(r), is, sx0);
    sy0 = fmaf(bfhi(r), is, sy0);
  }
  float sx = (sx0 + sx1) + (sx2 + sx3);
  float sy = (sy0 + sy1) + (sy2 + sy3);
  float aggx = 0.f, aggy = 0.f;
  if (degi > 0) {
    float2 tv = ((const float2*)(T + ((size_t)i << 7)))[lane];
    float isi = isd[i];
    float di = (float)degi;
    aggx = 0.5f * (isi * sx) + 0.5f * (di * tv.x);
    aggy = 0.5f * (isi * sy) + 0.5f * (di * tv.y);
  }
  float2 mmv = ((const float2*)mm)[lane];
  float2 vv = ((const float2*)var)[lane];
  float2 gv = ((const float2*)gamma)[lane];
  float2 bv = ((const float2*)beta)[lane];
  float2 res;
  res.x = (aggx - mmv.x) * rsqrtf(vv.x + BN_EPS) * gv.x + bv.x;
  res.y = (aggy - mmv.y) * rsqrtf(vv.y + BN_EPS) * gv.y + bv.y;
  ((float2*)(out + ((size_t)i << 7)))[lane] = res;
}

static inline size_t align_up(size_t x) { return (x + 255) & ~(size_t)255; }

extern "C" void kernel_launch(void* const* d_in, const int* in_sizes, int n_in,
                              void* d_out, int out_size, void* d_ws, size_t ws_size,
                              hipStream_t stream) {
  const int4* ep2 = (const int4*)d_in[0];
  const float* X = (const float*)d_in[1];
  const float* W = (const float*)d_in[2];
  const float* b = (const float*)d_in[3];
  const float* gamma = (const float*)d_in[4];
  const float* beta = (const float*)d_in[5];
  const float* mm = (const float*)d_in[6];
  const float* var = (const float*)d_in[7];
  float* out = (float*)d_out;

  const int ne = in_sizes[0] / 2;
  const int n = in_sizes[1] / 128;
  const int nblk = (n + 255) / 256;   // <= 256
  const int nbuck = (n + 63) >> 6;    // 782 for n=50000

  char* p = (char*)d_ws;
  int* deg = (int*)p;        p += align_up((size_t)n * 4);
  float* isd = (float*)p;    p += align_up((size_t)n * 4);
  int* offsets = (int*)p;    p += align_up((size_t)n * 4);
  int* bcnt = (int*)p;       p += align_up((size_t)nbuck * 4);
  int* bsum = (int*)p;       p += align_up((size_t)nblk * 4);
  int* boff = (int*)p;       p += align_up((size_t)nblk * 4);
  int* csr_dst = (int*)p;    p += align_up((size_t)ne * 4);
  unsigned* bins = (unsigned*)p; p += align_up((size_t)nbuck * BUCK_CAP * 4);
  float* T = (float*)p;      p += align_up((size_t)n * 128 * 4);
  unsigned* Tb = (unsigned*)p; p += align_up((size_t)n * 64 * 4);

  hipMemsetAsync(bcnt, 0, (size_t)nbuck * 4, stream);
  int nh = (ne + 1) / 2;
  k_bin<<<(nh + 255) / 256, 256, 0, stream>>>(ep2, ne, bcnt, bins);
  k_bcount<<<nbuck, 256, 0, stream>>>(bcnt, bins, n, deg);
  k_blocksum<<<nblk, 256, 0, stream>>>(deg, n, bsum);
  k_scan_bsums<<<1, 256, 0, stream>>>(bsum, nblk, boff);
  k_scan_final<<<nblk, 256, 0, stream>>>(deg, n, boff, offsets, isd);
  k_bfill<<<nbuck, 256, 0, stream>>>(bcnt, bins, offsets, n, csr_dst);
  k_gemm<<<(n + GEMM_BM - 1) / GEMM_BM, 256, 0, stream>>>(X, W, b, T, Tb, n);
  k_gather<<<(n + 3) / 4, 256, 0, stream>>>(T, Tb, deg, isd, offsets, csr_dst,
                                            mm, var, gamma, beta, out, n);
}

// Round 4
// 122.987 us; speedup vs baseline: 2.4460x; 2.4460x over previous
//
#include <hip/hip_runtime.h>
#include <math.h>

#define BN_EPS 0.001f
#define GEMM_BM 64
#define CHUNK 4096          // edges per chunk; nchunk = ceil(ne/CHUNK) must be <= 256
#define MAXBUCK 1024        // nbuck = ceil(n/64) must be <= 1024

__device__ inline unsigned bf16rne(float f) {
  unsigned u = __float_as_uint(f);
  return (u + 0x7fffu + ((u >> 16) & 1u)) >> 16;
}
__device__ inline float bflo(unsigned r) { return __uint_as_float(r << 16); }
__device__ inline float bfhi(unsigned r) { return __uint_as_float(r & 0xffff0000u); }

// ---------------- pass 1: per-chunk LDS histogram by bucket (src>>6) ----------------
__global__ __launch_bounds__(256) void k_ehist(const int2* __restrict__ ep, int ne,
                                               int nbuck, int* __restrict__ ghist) {
  __shared__ int h[MAXBUCK];
  int c = blockIdx.x, t = threadIdx.x;
  for (int i = t; i < nbuck; i += 256) h[i] = 0;
  __syncthreads();
  int base = c * CHUNK;
  int end = min(base + CHUNK, ne);
  for (int e = base + t; e < end; e += 256) atomicAdd(&h[ep[e].x >> 6], 1);
  __syncthreads();
  int* row = ghist + (size_t)c * nbuck;
  for (int i = t; i < nbuck; i += 256) row[i] = h[i];
}

// ---------------- pass 2a: per-bucket exclusive scan over chunks (in place) + totals ----
__global__ __launch_bounds__(256) void k_bscan(int* __restrict__ ghist, int nchunk,
                                               int nbuck, int* __restrict__ btot) {
  __shared__ int s0[256], s1[256];
  int b = blockIdx.x, t = threadIdx.x;
  int v = (t < nchunk) ? ghist[(size_t)t * nbuck + b] : 0;
  s0[t] = v;
  __syncthreads();
  int* src = s0; int* dst = s1;
  for (int off = 1; off < 256; off <<= 1) {
    int x = src[t];
    if (t >= off) x += src[t - off];
    dst[t] = x;
    __syncthreads();
    int* tmp = src; src = dst; dst = tmp;
  }
  if (t < nchunk) ghist[(size_t)t * nbuck + b] = src[t] - v;  // exclusive
  if (t == 0) btot[b] = src[255];                             // total
}

// ---------------- pass 2b: single-block exclusive scan of bucket totals ----------------
__global__ __launch_bounds__(1024) void k_bbase(const int* __restrict__ btot, int nbuck,
                                                int* __restrict__ bbase) {
  __shared__ int s0[1024], s1[1024];
  int t = threadIdx.x;
  int v = (t < nbuck) ? btot[t] : 0;
  s0[t] = v;
  __syncthreads();
  int* src = s0; int* dst = s1;
  for (int off = 1; off < 1024; off <<= 1) {
    int x = src[t];
    if (t >= off) x += src[t - off];
    dst[t] = x;
    __syncthreads();
    int* tmp = src; src = dst; dst = tmp;
  }
  if (t < nbuck) bbase[t] = src[t] - v;
}

// ---------------- pass 3: write packed records to exact slots (LDS cursors) ----------
// record: bits[16:0] = dst, bits[22:17] = src & 63
__global__ __launch_bounds__(256) void k_ebin(const int2* __restrict__ ep, int ne,
                                              int nbuck, const int* __restrict__ ghist,
                                              const int* __restrict__ bbase,
                                              unsigned* __restrict__ bins) {
  __shared__ int cur[MAXBUCK];
  int c = blockIdx.x, t = threadIdx.x;
  const int* row = ghist + (size_t)c * nbuck;
  for (int i = t; i < nbuck; i += 256) cur[i] = bbase[i] + row[i];
  __syncthreads();
  int base = c * CHUNK;
  int end = min(base + CHUNK, ne);
  for (int e = base + t; e < end; e += 256) {
    int2 p = ep[e];
    int pos = atomicAdd(&cur[p.x >> 6], 1);
    bins[pos] = (unsigned)p.y | ((unsigned)(p.x & 63) << 17);
  }
}

// ---------------- per-bucket LDS histogram -> deg ----------------
__global__ __launch_bounds__(256) void k_bcount(const int* __restrict__ bbase,
                                                const int* __restrict__ btot,
                                                const unsigned* __restrict__ bins,
                                                int n, int* __restrict__ deg) {
  __shared__ int h[64];
  int bk = blockIdx.x, t = threadIdx.x;
  if (t < 64) h[t] = 0;
  __syncthreads();
  int s = bbase[bk], cnt = btot[bk];
  for (int i = t; i < cnt; i += 256) atomicAdd(&h[bins[s + i] >> 17], 1);
  __syncthreads();
  if (t < 64) {
    int node = (bk << 6) + t;
    if (node < n) deg[node] = h[t];
  }
}

// ---------------- node-level scan (3 kernels) ----------------
__global__ void k_blocksum(const int* __restrict__ deg, int n, int* __restrict__ bsum) {
  __shared__ int sdata[256];
  int t = threadIdx.x;
  int i = blockIdx.x * 256 + t;
  sdata[t] = (i < n) ? deg[i] : 0;
  __syncthreads();
  for (int s = 128; s > 0; s >>= 1) {
    if (t < s) sdata[t] += sdata[t + s];
    __syncthreads();
  }
  if (t == 0) bsum[blockIdx.x] = sdata[0];
}

__global__ void k_scan_bsums(const int* __restrict__ bsum, int nb, int* __restrict__ boff) {
  __shared__ int s0[256], s1[256];
  int t = threadIdx.x;
  int v = (t < nb) ? bsum[t] : 0;
  s0[t] = v;
  __syncthreads();
  int* src = s0; int* dst = s1;
  for (int off = 1; off < 256; off <<= 1) {
    int x = src[t];
    if (t >= off) x += src[t - off];
    dst[t] = x;
    __syncthreads();
    int* tmp = src; src = dst; dst = tmp;
  }
  if (t < nb) boff[t] = src[t] - v;
}

__global__ void k_scan_final(const int* __restrict__ deg, int n, const int* __restrict__ boff,
                             int* __restrict__ offsets, float* __restrict__ isd) {
  __shared__ int s0[256], s1[256];
  int t = threadIdx.x;
  int i = blockIdx.x * 256 + t;
  int v = (i < n) ? deg[i] : 0;
  s0[t] = v;
  __syncthreads();
  int* src = s0; int* dst = s1;
  for (int off = 1; off < 256; off <<= 1) {
    int x = src[t];
    if (t >= off) x += src[t - off];
    dst[t] = x;
    __syncthreads();
    int* tmp = src; src = dst; dst = tmp;
  }
  if (i < n) {
    offsets[i] = src[t] - v + boff[blockIdx.x];
    isd[i] = 1.0f / sqrtf((float)deg[i]);  // deg==0 -> +inf, matches jnp.power
  }
}

// ---------------- per-bucket CSR fill with LDS cursors ----------------
__global__ __launch_bounds__(256) void k_bfill(const int* __restrict__ bbase,
                                               const int* __restrict__ btot,
                                               const unsigned* __restrict__ bins,
                                               const int* __restrict__ offsets, int n,
                                               int* __restrict__ csr_dst) {
  __shared__ int cur[64];
  int bk = blockIdx.x, t = threadIdx.x;
  if (t < 64) {
    int node = (bk << 6) + t;
    cur[t] = (node < n) ? offsets[node] : 0;
  }
  __syncthreads();
  int s = bbase[bk], cnt = btot[bk];
  for (int i = t; i < cnt; i += 256) {
    unsigned r = bins[s + i];
    int pos = atomicAdd(&cur[r >> 17], 1);
    csr_dst[pos] = (int)(r & 0x1FFFFu);
  }
}

// ---------------- fp32 GEMM: T = X @ W + b, also emits bf16-packed Tb ----------------
__global__ __launch_bounds__(256) void k_gemm(const float* __restrict__ X,
                                              const float* __restrict__ W,
                                              const float* __restrict__ b,
                                              float* __restrict__ T,
                                              unsigned* __restrict__ Tb, int M) {
  constexpr int LDA = 68;
  constexpr int LDW = 132;
  __shared__ float As[64 * LDA];
  __shared__ float Ws[64 * LDW];
  int tid = threadIdx.x;
  int brow = blockIdx.x * GEMM_BM;
  int rows_here = M - brow;
  if (rows_here > GEMM_BM) rows_here = GEMM_BM;
  int tx = tid & 15;
  int ty = tid >> 4;
  float acc[4][8] = {};
  for (int kt = 0; kt < 2; ++kt) {
    __syncthreads();
    for (int idx = tid; idx < 64 * 32; idx += 256) {
      int k = idx >> 5;
      int c4 = idx & 31;
      float4 v = ((const float4*)(W + ((kt * 64 + k) << 7)))[c4];
      *(float4*)&Ws[k * LDW + c4 * 4] = v;
    }
    for (int idx = tid; idx < 64 * 16; idx += 256) {
      int r = idx >> 4;
      int kq = idx & 15;
      float4 v = make_float4(0.f, 0.f, 0.f, 0.f);
      if (r < rows_here)
        v = ((const float4*)(X + (((size_t)(brow + r)) << 7) + kt * 64))[kq];
      As[(kq * 4 + 0) * LDA + r] = v.x;
      As[(kq * 4 + 1) * LDA + r] = v.y;
      As[(kq * 4 + 2) * LDA + r] = v.z;
      As[(kq * 4 + 3) * LDA + r] = v.w;
    }
    __syncthreads();
#pragma unroll 8
    for (int k = 0; k < 64; ++k) {
      float4 av = *(const float4*)&As[k * LDA + ty * 4];
      float4 w0 = *(const float4*)&Ws[k * LDW + tx * 8];
      float4 w1 = *(const float4*)&Ws[k * LDW + tx * 8 + 4];
      float a[4] = {av.x, av.y, av.z, av.w};
      float w[8] = {w0.x, w0.y, w0.z, w0.w, w1.x, w1.y, w1.z, w1.w};
#pragma unroll
      for (int r = 0; r < 4; ++r)
#pragma unroll
        for (int c = 0; c < 8; ++c)
          acc[r][c] = fmaf(a[r], w[c], acc[r][c]);
    }
  }
  float4 b0 = ((const float4*)b)[tx * 2];
  float4 b1 = ((const float4*)b)[tx * 2 + 1];
  float bias[8] = {b0.x, b0.y, b0.z, b0.w, b1.x, b1.y, b1.z, b1.w};
  for (int r = 0; r < 4; ++r) {
    int row = brow + ty * 4 + r;
    if (row < M) {
      float o[8];
#pragma unroll
      for (int c = 0; c < 8; ++c) o[c] = acc[r][c] + bias[c];
      float* dst = T + (((size_t)row) << 7) + tx * 8;
      *(float4*)dst = make_float4(o[0], o[1], o[2], o[3]);
      *(float4*)(dst + 4) = make_float4(o[4], o[5], o[6], o[7]);
      unsigned pk[4];
#pragma unroll
      for (int c = 0; c < 4; ++c)
        pk[c] = bf16rne(o[2 * c]) | (bf16rne(o[2 * c + 1]) << 16);
      *(uint4*)(Tb + (((size_t)row) << 6) + tx * 4) =
          make_uint4(pk[0], pk[1], pk[2], pk[3]);
    }
  }
}

// ---------------- gather: one wave per node, bf16 neighbor rows ----------------
__global__ __launch_bounds__(256) void k_gather(
    const float* __restrict__ T, const unsigned* __restrict__ Tb,
    const int* __restrict__ deg, const float* __restrict__ isd,
    const int* __restrict__ offsets, const int* __restrict__ csr_dst,
    const float* __restrict__ mm, const float* __restrict__ var,
    const float* __restrict__ gamma, const float* __restrict__ beta,
    float* __restrict__ out, int n) {
  int wave = threadIdx.x >> 6;
  int lane = threadIdx.x & 63;
  int i = blockIdx.x * 4 + wave;
  if (i >= n) return;
  int degi = deg[i];
  int start = offsets[i];
  float sx0 = 0.f, sy0 = 0.f, sx1 = 0.f, sy1 = 0.f;
  float sx2 = 0.f, sy2 = 0.f, sx3 = 0.f, sy3 = 0.f;
  int e = 0;
  for (; e + 4 <= degi; e += 4) {
    int d0 = csr_dst[start + e];
    int d1 = csr_dst[start + e + 1];
    int d2 = csr_dst[start + e + 2];
    int d3 = csr_dst[start + e + 3];
    unsigned r0 = Tb[((size_t)d0 << 6) + lane];
    unsigned r1 = Tb[((size_t)d1 << 6) + lane];
    unsigned r2 = Tb[((size_t)d2 << 6) + lane];
    unsigned r3 = Tb[((size_t)d3 << 6) + lane];
    float is0 = isd[d0], is1 = isd[d1], is2 = isd[d2], is3 = isd[d3];
    sx0 = fmaf(bflo(r0), is0, sx0); sy0 = fmaf(bfhi(r0), is0, sy0);
    sx1 = fmaf(bflo(r1), is1, sx1); sy1 = fmaf(bfhi(r1), is1, sy1);
    sx2 = fmaf(bflo(r2), is2, sx2); sy2 = fmaf(bfhi(r2), is2, sy2);
    sx3 = fmaf(bflo(r3), is3, sx3); sy3 = fmaf(bfhi(r3), is3, sy3);
  }
  for (; e < degi; ++e) {
    int d = csr_dst[start + e];
    unsigned r = Tb[((size_t)d << 6) + lane];
    float is = isd[d];
    sx0 = fmaf(bflo(r), is, sx0);
    sy0 = fmaf(bfhi(r), is, sy0);
  }
  float sx = (sx0 + sx1) + (sx2 + sx3);
  float sy = (sy0 + sy1) + (sy2 + sy3);
  float aggx = 0.f, aggy = 0.f;
  if (degi > 0) {
    float2 tv = ((const float2*)(T + ((size_t)i << 7)))[lane];
    float isi = isd[i];
    float di = (float)degi;
    aggx = 0.5f * (isi * sx) + 0.5f * (di * tv.x);
    aggy = 0.5f * (isi * sy) + 0.5f * (di * tv.y);
  }
  float2 mmv = ((const float2*)mm)[lane];
  float2 vv = ((const float2*)var)[lane];
  float2 gv = ((const float2*)gamma)[lane];
  float2 bv = ((const float2*)beta)[lane];
  float2 res;
  res.x = (aggx - mmv.x) * rsqrtf(vv.x + BN_EPS) * gv.x + bv.x;
  res.y = (aggy - mmv.y) * rsqrtf(vv.y + BN_EPS) * gv.y + bv.y;
  ((float2*)(out + ((size_t)i << 7)))[lane] = res;
}

static inline size_t align_up(size_t x) { return (x + 255) & ~(size_t)255; }

extern "C" void kernel_launch(void* const* d_in, const int* in_sizes, int n_in,
                              void* d_out, int out_size, void* d_ws, size_t ws_size,
                              hipStream_t stream) {
  const int2* ep = (const int2*)d_in[0];
  const float* X = (const float*)d_in[1];
  const float* W = (const float*)d_in[2];
  const float* b = (const float*)d_in[3];
  const float* gamma = (const float*)d_in[4];
  const float* beta = (const float*)d_in[5];
  const float* mm = (const float*)d_in[6];
  const float* var = (const float*)d_in[7];
  float* out = (float*)d_out;

  const int ne = in_sizes[0] / 2;
  const int n = in_sizes[1] / 128;
  const int nblk = (n + 255) / 256;      // node-scan blocks, <= 256
  const int nbuck = (n + 63) >> 6;       // <= MAXBUCK
  const int nchunk = (ne + CHUNK - 1) / CHUNK;  // <= 256

  char* p = (char*)d_ws;
  int* deg = (int*)p;        p += align_up((size_t)n * 4);
  float* isd = (float*)p;    p += align_up((size_t)n * 4);
  int* offsets = (int*)p;    p += align_up((size_t)n * 4);
  int* btot = (int*)p;       p += align_up((size_t)nbuck * 4);
  int* bbase = (int*)p;      p += align_up((size_t)nbuck * 4);
  int* bsum = (int*)p;       p += align_up((size_t)nblk * 4);
  int* boff = (int*)p;       p += align_up((size_t)nblk * 4);
  int* ghist = (int*)p;      p += align_up((size_t)nchunk * nbuck * 4);
  int* csr_dst = (int*)p;    p += align_up((size_t)ne * 4);
  unsigned* bins = (unsigned*)p; p += align_up((size_t)ne * 4);
  float* T = (float*)p;      p += align_up((size_t)n * 128 * 4);
  unsigned* Tb = (unsigned*)p; p += align_up((size_t)n * 64 * 4);

  k_ehist<<<nchunk, 256, 0, stream>>>(ep, ne, nbuck, ghist);
  k_bscan<<<nbuck, 256, 0, stream>>>(ghist, nchunk, nbuck, btot);
  k_bbase<<<1, 1024, 0, stream>>>(btot, nbuck, bbase);
  k_ebin<<<nchunk, 256, 0, stream>>>(ep, ne, nbuck, ghist, bbase, bins);
  k_bcount<<<nbuck, 256, 0, stream>>>(bbase, btot, bins, n, deg);
  k_blocksum<<<nblk, 256, 0, stream>>>(deg, n, bsum);
  k_scan_bsums<<<1, 256, 0, stream>>>(bsum, nblk, boff);
  k_scan_final<<<nblk, 256, 0, stream>>>(deg, n, boff, offsets, isd);
  k_bfill<<<nbuck, 256, 0, stream>>>(bbase, btot, bins, offsets, n, csr_dst);
  k_gemm<<<(n + GEMM_BM - 1) / GEMM_BM, 256, 0, stream>>>(X, W, b, T, Tb, n);
  k_gather<<<(n + 3) / 4, 256, 0, stream>>>(T, Tb, deg, isd, offsets, csr_dst,
                                            mm, var, gamma, beta, out, n);
}

// Round 5
// 116.691 us; speedup vs baseline: 2.5780x; 1.0540x over previous
//
#include <hip/hip_runtime.h>
#include <math.h>

#define BN_EPS 0.001f
#define CHUNK 4096          // edges per chunk; nchunk = ceil(ne/CHUNK) must be <= 256
#define MAXBUCK 1024        // nbuck = ceil(n/64) must be <= 1024

typedef __attribute__((ext_vector_type(8))) short bf16x8;
typedef __attribute__((ext_vector_type(4))) float f32x4;

__device__ inline unsigned bf16rne(float f) {
  unsigned u = __float_as_uint(f);
  return (u + 0x7fffu + ((u >> 16) & 1u)) >> 16;
}
__device__ inline float bflo(unsigned r) { return __uint_as_float(r << 16); }
__device__ inline float bfhi(unsigned r) { return __uint_as_float(r & 0xffff0000u); }

// ---------------- pass 1: per-chunk LDS histogram by bucket (src>>6) ----------------
__global__ __launch_bounds__(256) void k_ehist(const int2* __restrict__ ep, int ne,
                                               int nbuck, int* __restrict__ ghist) {
  __shared__ int h[MAXBUCK];
  int c = blockIdx.x, t = threadIdx.x;
  for (int i = t; i < nbuck; i += 256) h[i] = 0;
  __syncthreads();
  int base = c * CHUNK;
  int end = min(base + CHUNK, ne);
  for (int e = base + t; e < end; e += 256) atomicAdd(&h[ep[e].x >> 6], 1);
  __syncthreads();
  int* row = ghist + (size_t)c * nbuck;
  for (int i = t; i < nbuck; i += 256) row[i] = h[i];
}

// ---------------- pass 2a: per-bucket exclusive scan over chunks (in place) + totals ----
__global__ __launch_bounds__(256) void k_bscan(int* __restrict__ ghist, int nchunk,
                                               int nbuck, int* __restrict__ btot) {
  __shared__ int s0[256], s1[256];
  int b = blockIdx.x, t = threadIdx.x;
  int v = (t < nchunk) ? ghist[(size_t)t * nbuck + b] : 0;
  s0[t] = v;
  __syncthreads();
  int* src = s0; int* dst = s1;
  for (int off = 1; off < 256; off <<= 1) {
    int x = src[t];
    if (t >= off) x += src[t - off];
    dst[t] = x;
    __syncthreads();
    int* tmp = src; src = dst; dst = tmp;
  }
  if (t < nchunk) ghist[(size_t)t * nbuck + b] = src[t] - v;  // exclusive
  if (t == 0) btot[b] = src[255];                             // total
}

// ---------------- pass 2b: single-block exclusive scan of bucket totals ----------------
__global__ __launch_bounds__(1024) void k_bbase(const int* __restrict__ btot, int nbuck,
                                                int* __restrict__ bbase) {
  __shared__ int s0[1024], s1[1024];
  int t = threadIdx.x;
  int v = (t < nbuck) ? btot[t] : 0;
  s0[t] = v;
  __syncthreads();
  int* src = s0; int* dst = s1;
  for (int off = 1; off < 1024; off <<= 1) {
    int x = src[t];
    if (t >= off) x += src[t - off];
    dst[t] = x;
    __syncthreads();
    int* tmp = src; src = dst; dst = tmp;
  }
  if (t < nbuck) bbase[t] = src[t] - v;
}

// ---------------- pass 3: write packed records to exact slots (LDS cursors) ----------
// record: bits[16:0] = dst, bits[22:17] = src & 63
__global__ __launch_bounds__(256) void k_ebin(const int2* __restrict__ ep, int ne,
                                              int nbuck, const int* __restrict__ ghist,
                                              const int* __restrict__ bbase,
                                              unsigned* __restrict__ bins) {
  __shared__ int cur[MAXBUCK];
  int c = blockIdx.x, t = threadIdx.x;
  const int* row = ghist + (size_t)c * nbuck;
  for (int i = t; i < nbuck; i += 256) cur[i] = bbase[i] + row[i];
  __syncthreads();
  int base = c * CHUNK;
  int end = min(base + CHUNK, ne);
  for (int e = base + t; e < end; e += 256) {
    int2 p = ep[e];
    int pos = atomicAdd(&cur[p.x >> 6], 1);
    bins[pos] = (unsigned)p.y | ((unsigned)(p.x & 63) << 17);
  }
}

// ---------------- per-bucket LDS histogram -> deg ----------------
__global__ __launch_bounds__(256) void k_bcount(const int* __restrict__ bbase,
                                                const int* __restrict__ btot,
                                                const unsigned* __restrict__ bins,
                                                int n, int* __restrict__ deg) {
  __shared__ int h[64];
  int bk = blockIdx.x, t = threadIdx.x;
  if (t < 64) h[t] = 0;
  __syncthreads();
  int s = bbase[bk], cnt = btot[bk];
  for (int i = t; i < cnt; i += 256) atomicAdd(&h[bins[s + i] >> 17], 1);
  __syncthreads();
  if (t < 64) {
    int node = (bk << 6) + t;
    if (node < n) deg[node] = h[t];
  }
}

// ---------------- node-level scan (3 kernels) ----------------
__global__ void k_blocksum(const int* __restrict__ deg, int n, int* __restrict__ bsum) {
  __shared__ int sdata[256];
  int t = threadIdx.x;
  int i = blockIdx.x * 256 + t;
  sdata[t] = (i < n) ? deg[i] : 0;
  __syncthreads();
  for (int s = 128; s > 0; s >>= 1) {
    if (t < s) sdata[t] += sdata[t + s];
    __syncthreads();
  }
  if (t == 0) bsum[blockIdx.x] = sdata[0];
}

__global__ void k_scan_bsums(const int* __restrict__ bsum, int nb, int* __restrict__ boff) {
  __shared__ int s0[256], s1[256];
  int t = threadIdx.x;
  int v = (t < nb) ? bsum[t] : 0;
  s0[t] = v;
  __syncthreads();
  int* src = s0; int* dst = s1;
  for (int off = 1; off < 256; off <<= 1) {
    int x = src[t];
    if (t >= off) x += src[t - off];
    dst[t] = x;
    __syncthreads();
    int* tmp = src; src = dst; dst = tmp;
  }
  if (t < nb) boff[t] = src[t] - v;
}

__global__ void k_scan_final(const int* __restrict__ deg, int n, const int* __restrict__ boff,
                             int* __restrict__ offsets, float* __restrict__ isd) {
  __shared__ int s0[256], s1[256];
  int t = threadIdx.x;
  int i = blockIdx.x * 256 + t;
  int v = (i < n) ? deg[i] : 0;
  s0[t] = v;
  __syncthreads();
  int* src = s0; int* dst = s1;
  for (int off = 1; off < 256; off <<= 1) {
    int x = src[t];
    if (t >= off) x += src[t - off];
    dst[t] = x;
    __syncthreads();
    int* tmp = src; src = dst; dst = tmp;
  }
  if (i < n) {
    offsets[i] = src[t] - v + boff[blockIdx.x];
    isd[i] = 1.0f / sqrtf((float)deg[i]);  // deg==0 -> +inf, matches jnp.power
  }
}

// ---------------- per-bucket CSR fill with LDS cursors ----------------
__global__ __launch_bounds__(256) void k_bfill(const int* __restrict__ bbase,
                                               const int* __restrict__ btot,
                                               const unsigned* __restrict__ bins,
                                               const int* __restrict__ offsets, int n,
                                               int* __restrict__ csr_dst) {
  __shared__ int cur[64];
  int bk = blockIdx.x, t = threadIdx.x;
  if (t < 64) {
    int node = (bk << 6) + t;
    cur[t] = (node < n) ? offsets[node] : 0;
  }
  __syncthreads();
  int s = bbase[bk], cnt = btot[bk];
  for (int i = t; i < cnt; i += 256) {
    unsigned r = bins[s + i];
    int pos = atomicAdd(&cur[r >> 17], 1);
    csr_dst[pos] = (int)(r & 0x1FFFFu);
  }
}

// ---------------- split-bf16 MFMA GEMM: T = X @ W + b (fp32-grade via 3x bf16) --------
// Block: 256 thr = 4 waves, 128 rows/block, 32 rows/wave (2 x 16-row tiles).
// LDS: W transposed+split -> Wh/Wl[col][k] bf16, XOR chunk-swizzle, 64KB total.
__global__ __launch_bounds__(256) void k_gemm(const float* __restrict__ X,
                                              const float* __restrict__ W,
                                              const float* __restrict__ b,
                                              float* __restrict__ T,
                                              unsigned* __restrict__ Tb, int M) {
  __shared__ unsigned short Wh[128 * 128];  // [col][k], chunk-swizzled, 32KB
  __shared__ unsigned short Wl[128 * 128];
  int tid = threadIdx.x;
  // stage W: read row-major coalesced, split, write transposed+swizzled
#pragma unroll
  for (int it = 0; it < 16; ++it) {
    int q = tid + it * 256;        // float4 index, 4096 total
    int k = q >> 5;                // (q*4)>>7
    int n0 = (q & 31) * 4;
    float4 v = ((const float4*)W)[q];
    float vv[4] = {v.x, v.y, v.z, v.w};
#pragma unroll
    for (int j = 0; j < 4; ++j) {
      int col = n0 + j;
      float x = vv[j];
      unsigned short h = (unsigned short)(__float_as_uint(x) >> 16);  // trunc hi
      float rem = x - __uint_as_float((unsigned)h << 16);
      unsigned short l = (unsigned short)bf16rne(rem);
      int addr = col * 128 + (((k >> 3) ^ (col & 7)) << 3) + (k & 7);
      Wh[addr] = h;
      Wl[addr] = l;
    }
  }
  __syncthreads();

  int wave = tid >> 6, lane = tid & 63;
  int r16 = lane & 15;   // A row-in-tile / B col-in-tile / D col-in-tile
  int kq = lane >> 4;    // k sub-block 0..3
  int waverow = blockIdx.x * 128 + wave * 32;

  // preload + split A fragments: rt in {0,1}, ks in 0..3
  bf16x8 ah[2][4], al[2][4];
#pragma unroll
  for (int rt = 0; rt < 2; ++rt) {
    int row = waverow + rt * 16 + r16;
    bool ok = (row < M);
    const float* xr = X + ((size_t)row << 7);
#pragma unroll
    for (int ks = 0; ks < 4; ++ks) {
      int k0 = ks * 32 + kq * 8;
      float4 v0 = ok ? *(const float4*)(xr + k0) : make_float4(0.f, 0.f, 0.f, 0.f);
      float4 v1 = ok ? *(const float4*)(xr + k0 + 4) : make_float4(0.f, 0.f, 0.f, 0.f);
      float f[8] = {v0.x, v0.y, v0.z, v0.w, v1.x, v1.y, v1.z, v1.w};
      bf16x8 h8, l8;
#pragma unroll
      for (int j = 0; j < 8; ++j) {
        unsigned short h = (unsigned short)(__float_as_uint(f[j]) >> 16);
        float rem = f[j] - __uint_as_float((unsigned)h << 16);
        h8[j] = (short)h;
        l8[j] = (short)bf16rne(rem);
      }
      ah[rt][ks] = h8;
      al[rt][ks] = l8;
    }
  }

  f32x4 acc[2][8] = {};
#pragma unroll
  for (int ks = 0; ks < 4; ++ks) {
#pragma unroll
    for (int ct = 0; ct < 8; ++ct) {
      int col = ct * 16 + r16;
      int chunk = (ks * 4 + kq) ^ (col & 7);
      bf16x8 bh = *(const bf16x8*)&Wh[col * 128 + chunk * 8];
      bf16x8 bl = *(const bf16x8*)&Wl[col * 128 + chunk * 8];
#pragma unroll
      for (int rt = 0; rt < 2; ++rt) {
        acc[rt][ct] = __builtin_amdgcn_mfma_f32_16x16x32_bf16(ah[rt][ks], bh, acc[rt][ct], 0, 0, 0);
        acc[rt][ct] = __builtin_amdgcn_mfma_f32_16x16x32_bf16(ah[rt][ks], bl, acc[rt][ct], 0, 0, 0);
        acc[rt][ct] = __builtin_amdgcn_mfma_f32_16x16x32_bf16(al[rt][ks], bh, acc[rt][ct], 0, 0, 0);
      }
    }
  }

  // epilogue: bias, store fp32 T (coalesced), pack bf16 Tb via shfl pairing
  float bias[8];
#pragma unroll
  for (int ct = 0; ct < 8; ++ct) bias[ct] = b[ct * 16 + r16];
#pragma unroll
  for (int rt = 0; rt < 2; ++rt) {
#pragma unroll
    for (int ct = 0; ct < 8; ++ct) {
      int col = ct * 16 + r16;
      f32x4 a4 = acc[rt][ct];
#pragma unroll
      for (int r = 0; r < 4; ++r) {
        float v = a4[r] + bias[ct];
        int row = waverow + rt * 16 + kq * 4 + r;
        if (row < M) T[((size_t)row << 7) + col] = v;
        float other = __shfl_xor(v, 1);  // partner column (col^1), same row
        if (row < M && !(r16 & 1)) {
          unsigned pk = bf16rne(v) | (bf16rne(other) << 16);
          Tb[((size_t)row << 6) + ct * 8 + (r16 >> 1)] = pk;
        }
      }
    }
  }
}

// ---------------- gather: one wave per node, bf16 neighbor rows ----------------
__global__ __launch_bounds__(256) void k_gather(
    const float* __restrict__ T, const unsigned* __restrict__ Tb,
    const int* __restrict__ deg, const float* __restrict__ isd,
    const int* __restrict__ offsets, const int* __restrict__ csr_dst,
    const float* __restrict__ mm, const float* __restrict__ var,
    const float* __restrict__ gamma, const float* __restrict__ beta,
    float* __restrict__ out, int n) {
  int wave = threadIdx.x >> 6;
  int lane = threadIdx.x & 63;
  int i = blockIdx.x * 4 + wave;
  if (i >= n) return;
  int degi = deg[i];
  int start = offsets[i];
  float sx0 = 0.f, sy0 = 0.f, sx1 = 0.f, sy1 = 0.f;
  float sx2 = 0.f, sy2 = 0.f, sx3 = 0.f, sy3 = 0.f;
  int e = 0;
  for (; e + 4 <= degi; e += 4) {
    int d0 = csr_dst[start + e];
    int d1 = csr_dst[start + e + 1];
    int d2 = csr_dst[start + e + 2];
    int d3 = csr_dst[start + e + 3];
    unsigned r0 = Tb[((size_t)d0 << 6) + lane];
    unsigned r1 = Tb[((size_t)d1 << 6) + lane];
    unsigned r2 = Tb[((size_t)d2 << 6) + lane];
    unsigned r3 = Tb[((size_t)d3 << 6) + lane];
    float is0 = isd[d0], is1 = isd[d1], is2 = isd[d2], is3 = isd[d3];
    sx0 = fmaf(bflo(r0), is0, sx0); sy0 = fmaf(bfhi(r0), is0, sy0);
    sx1 = fmaf(bflo(r1), is1, sx1); sy1 = fmaf(bfhi(r1), is1, sy1);
    sx2 = fmaf(bflo(r2), is2, sx2); sy2 = fmaf(bfhi(r2), is2, sy2);
    sx3 = fmaf(bflo(r3), is3, sx3); sy3 = fmaf(bfhi(r3), is3, sy3);
  }
  for (; e < degi; ++e) {
    int d = csr_dst[start + e];
    unsigned r = Tb[((size_t)d << 6) + lane];
    float is = isd[d];
    sx0 = fmaf(bflo(r), is, sx0);
    sy0 = fmaf(bfhi(r), is, sy0);
  }
  float sx = (sx0 + sx1) + (sx2 + sx3);
  float sy = (sy0 + sy1) + (sy2 + sy3);
  float aggx = 0.f, aggy = 0.f;
  if (degi > 0) {
    float2 tv = ((const float2*)(T + ((size_t)i << 7)))[lane];
    float isi = isd[i];
    float di = (float)degi;
    aggx = 0.5f * (isi * sx) + 0.5f * (di * tv.x);
    aggy = 0.5f * (isi * sy) + 0.5f * (di * tv.y);
  }
  float2 mmv = ((const float2*)mm)[lane];
  float2 vv = ((const float2*)var)[lane];
  float2 gv = ((const float2*)gamma)[lane];
  float2 bv = ((const float2*)beta)[lane];
  float2 res;
  res.x = (aggx - mmv.x) * rsqrtf(vv.x + BN_EPS) * gv.x + bv.x;
  res.y = (aggy - mmv.y) * rsqrtf(vv.y + BN_EPS) * gv.y + bv.y;
  ((float2*)(out + ((size_t)i << 7)))[lane] = res;
}

static inline size_t align_up(size_t x) { return (x + 255) & ~(size_t)255; }

extern "C" void kernel_launch(void* const* d_in, const int* in_sizes, int n_in,
                              void* d_out, int out_size, void* d_ws, size_t ws_size,
                              hipStream_t stream) {
  const int2* ep = (const int2*)d_in[0];
  const float* X = (const float*)d_in[1];
  const float* W = (const float*)d_in[2];
  const float* b = (const float*)d_in[3];
  const float* gamma = (const float*)d_in[4];
  const float* beta = (const float*)d_in[5];
  const float* mm = (const float*)d_in[6];
  const float* var = (const float*)d_in[7];
  float* out = (float*)d_out;

  const int ne = in_sizes[0] / 2;
  const int n = in_sizes[1] / 128;
  const int nblk = (n + 255) / 256;      // node-scan blocks, <= 256
  const int nbuck = (n + 63) >> 6;       // <= MAXBUCK
  const int nchunk = (ne + CHUNK - 1) / CHUNK;  // <= 256

  char* p = (char*)d_ws;
  int* deg = (int*)p;        p += align_up((size_t)n * 4);
  float* isd = (float*)p;    p += align_up((size_t)n * 4);
  int* offsets = (int*)p;    p += align_up((size_t)n * 4);
  int* btot = (int*)p;       p += align_up((size_t)nbuck * 4);
  int* bbase = (int*)p;      p += align_up((size_t)nbuck * 4);
  int* bsum = (int*)p;       p += align_up((size_t)nblk * 4);
  int* boff = (int*)p;       p += align_up((size_t)nblk * 4);
  int* ghist = (int*)p;      p += align_up((size_t)nchunk * nbuck * 4);
  int* csr_dst = (int*)p;    p += align_up((size_t)ne * 4);
  unsigned* bins = (unsigned*)p; p += align_up((size_t)ne * 4);
  float* T = (float*)p;      p += align_up((size_t)n * 128 * 4);
  unsigned* Tb = (unsigned*)p; p += align_up((size_t)n * 64 * 4);

  k_ehist<<<nchunk, 256, 0, stream>>>(ep, ne, nbuck, ghist);
  k_bscan<<<nbuck, 256, 0, stream>>>(ghist, nchunk, nbuck, btot);
  k_bbase<<<1, 1024, 0, stream>>>(btot, nbuck, bbase);
  k_ebin<<<nchunk, 256, 0, stream>>>(ep, ne, nbuck, ghist, bbase, bins);
  k_bcount<<<nbuck, 256, 0, stream>>>(bbase, btot, bins, n, deg);
  k_blocksum<<<nblk, 256, 0, stream>>>(deg, n, bsum);
  k_scan_bsums<<<1, 256, 0, stream>>>(bsum, nblk, boff);
  k_scan_final<<<nblk, 256, 0, stream>>>(deg, n, boff, offsets, isd);
  k_bfill<<<nbuck, 256, 0, stream>>>(bbase, btot, bins, offsets, n, csr_dst);
  k_gemm<<<(n + 127) / 128, 256, 0, stream>>>(X, W, b, T, Tb, n);
  k_gather<<<(n + 3) / 4, 256, 0, stream>>>(T, Tb, deg, isd, offsets, csr_dst,
                                            mm, var, gamma, beta, out, n);
}

// Round 6
// 108.369 us; speedup vs baseline: 2.7759x; 1.0768x over previous
//
#include <hip/hip_runtime.h>
#include <math.h>

#define BN_EPS 0.001f
#define CHUNK 4096          // edges per chunk; nchunk = ceil(ne/CHUNK) must be <= 256
#define MAXBUCK 1024        // nbuck = ceil(n/64) must be <= 1024

typedef __attribute__((ext_vector_type(8))) short bf16x8;
typedef __attribute__((ext_vector_type(4))) float f32x4;

__device__ inline unsigned bf16rne(float f) {
  unsigned u = __float_as_uint(f);
  return (u + 0x7fffu + ((u >> 16) & 1u)) >> 16;
}
__device__ inline float bflo(unsigned r) { return __uint_as_float(r << 16); }
__device__ inline float bfhi(unsigned r) { return __uint_as_float(r & 0xffff0000u); }

// ---------------- pass 1: per-chunk LDS histogram by bucket (src>>6) ----------------
__global__ __launch_bounds__(256) void k_ehist(const int2* __restrict__ ep, int ne,
                                               int nbuck, int* __restrict__ ghist) {
  __shared__ int h[MAXBUCK];
  int c = blockIdx.x, t = threadIdx.x;
  for (int i = t; i < nbuck; i += 256) h[i] = 0;
  __syncthreads();
  int base = c * CHUNK;
  int end = min(base + CHUNK, ne);
  for (int e = base + t; e < end; e += 256) atomicAdd(&h[ep[e].x >> 6], 1);
  __syncthreads();
  int* row = ghist + (size_t)c * nbuck;
  for (int i = t; i < nbuck; i += 256) row[i] = h[i];
}

// ---------------- pass 2a: per-bucket exclusive scan over chunks (in place) + totals ----
__global__ __launch_bounds__(256) void k_bscan(int* __restrict__ ghist, int nchunk,
                                               int nbuck, int* __restrict__ btot) {
  __shared__ int s0[256], s1[256];
  int b = blockIdx.x, t = threadIdx.x;
  int v = (t < nchunk) ? ghist[(size_t)t * nbuck + b] : 0;
  s0[t] = v;
  __syncthreads();
  int* src = s0; int* dst = s1;
  for (int off = 1; off < 256; off <<= 1) {
    int x = src[t];
    if (t >= off) x += src[t - off];
    dst[t] = x;
    __syncthreads();
    int* tmp = src; src = dst; dst = tmp;
  }
  if (t < nchunk) ghist[(size_t)t * nbuck + b] = src[t] - v;  // exclusive
  if (t == 0) btot[b] = src[255];                             // total
}

// ---------------- pass 2b: single-block exclusive scan of bucket totals ----------------
__global__ __launch_bounds__(1024) void k_bbase(const int* __restrict__ btot, int nbuck,
                                                int* __restrict__ bbase) {
  __shared__ int s0[1024], s1[1024];
  int t = threadIdx.x;
  int v = (t < nbuck) ? btot[t] : 0;
  s0[t] = v;
  __syncthreads();
  int* src = s0; int* dst = s1;
  for (int off = 1; off < 1024; off <<= 1) {
    int x = src[t];
    if (t >= off) x += src[t - off];
    dst[t] = x;
    __syncthreads();
    int* tmp = src; src = dst; dst = tmp;
  }
  if (t < nbuck) bbase[t] = src[t] - v;
}

// ---------------- pass 3: write packed records to exact slots (LDS cursors) ----------
// record: bits[16:0] = dst, bits[22:17] = src & 63
__global__ __launch_bounds__(256) void k_ebin(const int2* __restrict__ ep, int ne,
                                              int nbuck, const int* __restrict__ ghist,
                                              const int* __restrict__ bbase,
                                              unsigned* __restrict__ bins) {
  __shared__ int cur[MAXBUCK];
  int c = blockIdx.x, t = threadIdx.x;
  const int* row = ghist + (size_t)c * nbuck;
  for (int i = t; i < nbuck; i += 256) cur[i] = bbase[i] + row[i];
  __syncthreads();
  int base = c * CHUNK;
  int end = min(base + CHUNK, ne);
  for (int e = base + t; e < end; e += 256) {
    int2 p = ep[e];
    int pos = atomicAdd(&cur[p.x >> 6], 1);
    bins[pos] = (unsigned)p.y | ((unsigned)(p.x & 63) << 17);
  }
}

// ---------------- per-bucket LDS histogram -> deg ----------------
__global__ __launch_bounds__(256) void k_bcount(const int* __restrict__ bbase,
                                                const int* __restrict__ btot,
                                                const unsigned* __restrict__ bins,
                                                int n, int* __restrict__ deg) {
  __shared__ int h[64];
  int bk = blockIdx.x, t = threadIdx.x;
  if (t < 64) h[t] = 0;
  __syncthreads();
  int s = bbase[bk], cnt = btot[bk];
  for (int i = t; i < cnt; i += 256) atomicAdd(&h[bins[s + i] >> 17], 1);
  __syncthreads();
  if (t < 64) {
    int node = (bk << 6) + t;
    if (node < n) deg[node] = h[t];
  }
}

// ---------------- node-level scan (3 kernels) ----------------
__global__ void k_blocksum(const int* __restrict__ deg, int n, int* __restrict__ bsum) {
  __shared__ int sdata[256];
  int t = threadIdx.x;
  int i = blockIdx.x * 256 + t;
  sdata[t] = (i < n) ? deg[i] : 0;
  __syncthreads();
  for (int s = 128; s > 0; s >>= 1) {
    if (t < s) sdata[t] += sdata[t + s];
    __syncthreads();
  }
  if (t == 0) bsum[blockIdx.x] = sdata[0];
}

__global__ void k_scan_bsums(const int* __restrict__ bsum, int nb, int* __restrict__ boff) {
  __shared__ int s0[256], s1[256];
  int t = threadIdx.x;
  int v = (t < nb) ? bsum[t] : 0;
  s0[t] = v;
  __syncthreads();
  int* src = s0; int* dst = s1;
  for (int off = 1; off < 256; off <<= 1) {
    int x = src[t];
    if (t >= off) x += src[t - off];
    dst[t] = x;
    __syncthreads();
    int* tmp = src; src = dst; dst = tmp;
  }
  if (t < nb) boff[t] = src[t] - v;
}

__global__ void k_scan_final(const int* __restrict__ deg, int n, const int* __restrict__ boff,
                             int* __restrict__ offsets, float* __restrict__ isd) {
  __shared__ int s0[256], s1[256];
  int t = threadIdx.x;
  int i = blockIdx.x * 256 + t;
  int v = (i < n) ? deg[i] : 0;
  s0[t] = v;
  __syncthreads();
  int* src = s0; int* dst = s1;
  for (int off = 1; off < 256; off <<= 1) {
    int x = src[t];
    if (t >= off) x += src[t - off];
    dst[t] = x;
    __syncthreads();
    int* tmp = src; src = dst; dst = tmp;
  }
  if (i < n) {
    offsets[i] = src[t] - v + boff[blockIdx.x];
    isd[i] = 1.0f / sqrtf((float)deg[i]);  // deg==0 -> +inf, matches jnp.power
  }
}

// ---------------- per-bucket CSR fill with LDS cursors ----------------
__global__ __launch_bounds__(256) void k_bfill(const int* __restrict__ bbase,
                                               const int* __restrict__ btot,
                                               const unsigned* __restrict__ bins,
                                               const int* __restrict__ offsets, int n,
                                               int* __restrict__ csr_dst) {
  __shared__ int cur[64];
  int bk = blockIdx.x, t = threadIdx.x;
  if (t < 64) {
    int node = (bk << 6) + t;
    cur[t] = (node < n) ? offsets[node] : 0;
  }
  __syncthreads();
  int s = bbase[bk], cnt = btot[bk];
  for (int i = t; i < cnt; i += 256) {
    unsigned r = bins[s + i];
    int pos = atomicAdd(&cur[r >> 17], 1);
    csr_dst[pos] = (int)(r & 0x1FFFFu);
  }
}

// ---------------- W split+transpose into fragment-major layout (once) ----------------
// For frag (ct,ks): 64 lanes x 8 shorts contiguous. col = ct*16+(lane&15),
// k = ks*32+(lane>>4)*8+j. Wh/Wl each 128*128 shorts (32KB).
__global__ __launch_bounds__(256) void k_wsplit(const float* __restrict__ W,
                                                unsigned short* __restrict__ Wh,
                                                unsigned short* __restrict__ Wl) {
  int g = blockIdx.x * 256 + threadIdx.x;  // 0..2047
  int frag = g >> 6;                       // 0..31 = ct*4+ks
  int lane = g & 63;
  int ct = frag >> 2, ks = frag & 3;
  int col = ct * 16 + (lane & 15);
  int k0 = ks * 32 + (lane >> 4) * 8;
  unsigned short h8[8], l8[8];
#pragma unroll
  for (int j = 0; j < 8; ++j) {
    float x = W[(size_t)(k0 + j) * 128 + col];
    unsigned short h = (unsigned short)(__float_as_uint(x) >> 16);  // trunc hi
    float rem = x - __uint_as_float((unsigned)h << 16);
    h8[j] = h;
    l8[j] = (unsigned short)bf16rne(rem);
  }
  *(uint4*)&Wh[(size_t)frag * 512 + lane * 8] = *(uint4*)h8;
  *(uint4*)&Wl[(size_t)frag * 512 + lane * 8] = *(uint4*)l8;
}

// ---------------- split-bf16 MFMA GEMM, no LDS: T = X @ W + b ----------------
// 256 thr = 4 waves, 128 rows/block, 32 rows/wave (2 x 16-row tiles).
// B-fragments loaded fragment-major from L2-resident Wh/Wl.
__global__ __launch_bounds__(256) void k_gemm(const float* __restrict__ X,
                                              const unsigned short* __restrict__ Wh,
                                              const unsigned short* __restrict__ Wl,
                                              const float* __restrict__ b,
                                              float* __restrict__ T,
                                              unsigned* __restrict__ Tb, int M) {
  int tid = threadIdx.x;
  int wave = tid >> 6, lane = tid & 63;
  int r16 = lane & 15;   // A row-in-tile / B col-in-tile / D col-in-tile
  int kq = lane >> 4;    // k sub-block 0..3
  int waverow = blockIdx.x * 128 + wave * 32;

  // load + split A fragments: rt in {0,1}, ks in 0..3
  bf16x8 ah[2][4], al[2][4];
#pragma unroll
  for (int rt = 0; rt < 2; ++rt) {
    int row = waverow + rt * 16 + r16;
    bool ok = (row < M);
    const float* xr = X + ((size_t)row << 7);
#pragma unroll
    for (int ks = 0; ks < 4; ++ks) {
      int k0 = ks * 32 + kq * 8;
      float4 v0 = ok ? *(const float4*)(xr + k0) : make_float4(0.f, 0.f, 0.f, 0.f);
      float4 v1 = ok ? *(const float4*)(xr + k0 + 4) : make_float4(0.f, 0.f, 0.f, 0.f);
      float f[8] = {v0.x, v0.y, v0.z, v0.w, v1.x, v1.y, v1.z, v1.w};
      bf16x8 h8, l8;
#pragma unroll
      for (int j = 0; j < 8; ++j) {
        unsigned short h = (unsigned short)(__float_as_uint(f[j]) >> 16);
        float rem = f[j] - __uint_as_float((unsigned)h << 16);
        h8[j] = (short)h;
        l8[j] = (short)bf16rne(rem);
      }
      ah[rt][ks] = h8;
      al[rt][ks] = l8;
    }
  }

  f32x4 acc[2][8] = {};
#pragma unroll
  for (int ks = 0; ks < 4; ++ks) {
#pragma unroll
    for (int ct = 0; ct < 8; ++ct) {
      int frag = ct * 4 + ks;
      bf16x8 bh = *(const bf16x8*)&Wh[(size_t)frag * 512 + lane * 8];
      bf16x8 bl = *(const bf16x8*)&Wl[(size_t)frag * 512 + lane * 8];
#pragma unroll
      for (int rt = 0; rt < 2; ++rt) {
        acc[rt][ct] = __builtin_amdgcn_mfma_f32_16x16x32_bf16(ah[rt][ks], bh, acc[rt][ct], 0, 0, 0);
        acc[rt][ct] = __builtin_amdgcn_mfma_f32_16x16x32_bf16(ah[rt][ks], bl, acc[rt][ct], 0, 0, 0);
        acc[rt][ct] = __builtin_amdgcn_mfma_f32_16x16x32_bf16(al[rt][ks], bh, acc[rt][ct], 0, 0, 0);
      }
    }
  }

  // epilogue: bias, store fp32 T (coalesced-ish), pack bf16 Tb via shfl pairing
  float bias[8];
#pragma unroll
  for (int ct = 0; ct < 8; ++ct) bias[ct] = b[ct * 16 + r16];
#pragma unroll
  for (int rt = 0; rt < 2; ++rt) {
#pragma unroll
    for (int ct = 0; ct < 8; ++ct) {
      int col = ct * 16 + r16;
      f32x4 a4 = acc[rt][ct];
#pragma unroll
      for (int r = 0; r < 4; ++r) {
        float v = a4[r] + bias[ct];
        int row = waverow + rt * 16 + kq * 4 + r;
        if (row < M) T[((size_t)row << 7) + col] = v;
        float other = __shfl_xor(v, 1);  // partner column (col^1), same row
        if (row < M && !(r16 & 1)) {
          unsigned pk = bf16rne(v) | (bf16rne(other) << 16);
          Tb[((size_t)row << 6) + ct * 8 + (r16 >> 1)] = pk;
        }
      }
    }
  }
}

// ---------------- gather: one wave per node, bf16 neighbor rows ----------------
__global__ __launch_bounds__(256) void k_gather(
    const float* __restrict__ T, const unsigned* __restrict__ Tb,
    const int* __restrict__ deg, const float* __restrict__ isd,
    const int* __restrict__ offsets, const int* __restrict__ csr_dst,
    const float* __restrict__ mm, const float* __restrict__ var,
    const float* __restrict__ gamma, const float* __restrict__ beta,
    float* __restrict__ out, int n) {
  int wave = threadIdx.x >> 6;
  int lane = threadIdx.x & 63;
  int i = blockIdx.x * 4 + wave;
  if (i >= n) return;
  int degi = deg[i];
  int start = offsets[i];
  float sx0 = 0.f, sy0 = 0.f, sx1 = 0.f, sy1 = 0.f;
  float sx2 = 0.f, sy2 = 0.f, sx3 = 0.f, sy3 = 0.f;
  int e = 0;
  for (; e + 4 <= degi; e += 4) {
    int d0 = csr_dst[start + e];
    int d1 = csr_dst[start + e + 1];
    int d2 = csr_dst[start + e + 2];
    int d3 = csr_dst[start + e + 3];
    unsigned r0 = Tb[((size_t)d0 << 6) + lane];
    unsigned r1 = Tb[((size_t)d1 << 6) + lane];
    unsigned r2 = Tb[((size_t)d2 << 6) + lane];
    unsigned r3 = Tb[((size_t)d3 << 6) + lane];
    float is0 = isd[d0], is1 = isd[d1], is2 = isd[d2], is3 = isd[d3];
    sx0 = fmaf(bflo(r0), is0, sx0); sy0 = fmaf(bfhi(r0), is0, sy0);
    sx1 = fmaf(bflo(r1), is1, sx1); sy1 = fmaf(bfhi(r1), is1, sy1);
    sx2 = fmaf(bflo(r2), is2, sx2); sy2 = fmaf(bfhi(r2), is2, sy2);
    sx3 = fmaf(bflo(r3), is3, sx3); sy3 = fmaf(bfhi(r3), is3, sy3);
  }
  for (; e < degi; ++e) {
    int d = csr_dst[start + e];
    unsigned r = Tb[((size_t)d << 6) + lane];
    float is = isd[d];
    sx0 = fmaf(bflo(r), is, sx0);
    sy0 = fmaf(bfhi(r), is, sy0);
  }
  float sx = (sx0 + sx1) + (sx2 + sx3);
  float sy = (sy0 + sy1) + (sy2 + sy3);
  float aggx = 0.f, aggy = 0.f;
  if (degi > 0) {
    float2 tv = ((const float2*)(T + ((size_t)i << 7)))[lane];
    float isi = isd[i];
    float di = (float)degi;
    aggx = 0.5f * (isi * sx) + 0.5f * (di * tv.x);
    aggy = 0.5f * (isi * sy) + 0.5f * (di * tv.y);
  }
  float2 mmv = ((const float2*)mm)[lane];
  float2 vv = ((const float2*)var)[lane];
  float2 gv = ((const float2*)gamma)[lane];
  float2 bv = ((const float2*)beta)[lane];
  float2 res;
  res.x = (aggx - mmv.x) * rsqrtf(vv.x + BN_EPS) * gv.x + bv.x;
  res.y = (aggy - mmv.y) * rsqrtf(vv.y + BN_EPS) * gv.y + bv.y;
  ((float2*)(out + ((size_t)i << 7)))[lane] = res;
}

static inline size_t align_up(size_t x) { return (x + 255) & ~(size_t)255; }

extern "C" void kernel_launch(void* const* d_in, const int* in_sizes, int n_in,
                              void* d_out, int out_size, void* d_ws, size_t ws_size,
                              hipStream_t stream) {
  const int2* ep = (const int2*)d_in[0];
  const float* X = (const float*)d_in[1];
  const float* W = (const float*)d_in[2];
  const float* b = (const float*)d_in[3];
  const float* gamma = (const float*)d_in[4];
  const float* beta = (const float*)d_in[5];
  const float* mm = (const float*)d_in[6];
  const float* var = (const float*)d_in[7];
  float* out = (float*)d_out;

  const int ne = in_sizes[0] / 2;
  const int n = in_sizes[1] / 128;
  const int nblk = (n + 255) / 256;      // node-scan blocks, <= 256
  const int nbuck = (n + 63) >> 6;       // <= MAXBUCK
  const int nchunk = (ne + CHUNK - 1) / CHUNK;  // <= 256

  char* p = (char*)d_ws;
  int* deg = (int*)p;        p += align_up((size_t)n * 4);
  float* isd = (float*)p;    p += align_up((size_t)n * 4);
  int* offsets = (int*)p;    p += align_up((size_t)n * 4);
  int* btot = (int*)p;       p += align_up((size_t)nbuck * 4);
  int* bbase = (int*)p;      p += align_up((size_t)nbuck * 4);
  int* bsum = (int*)p;       p += align_up((size_t)nblk * 4);
  int* boff = (int*)p;       p += align_up((size_t)nblk * 4);
  int* ghist = (int*)p;      p += align_up((size_t)nchunk * nbuck * 4);
  int* csr_dst = (int*)p;    p += align_up((size_t)ne * 4);
  unsigned* bins = (unsigned*)p; p += align_up((size_t)ne * 4);
  unsigned short* Wh = (unsigned short*)p; p += align_up((size_t)128 * 128 * 2);
  unsigned short* Wl = (unsigned short*)p; p += align_up((size_t)128 * 128 * 2);
  float* T = (float*)p;      p += align_up((size_t)n * 128 * 4);
  unsigned* Tb = (unsigned*)p; p += align_up((size_t)n * 64 * 4);

  k_ehist<<<nchunk, 256, 0, stream>>>(ep, ne, nbuck, ghist);
  k_bscan<<<nbuck, 256, 0, stream>>>(ghist, nchunk, nbuck, btot);
  k_bbase<<<1, 1024, 0, stream>>>(btot, nbuck, bbase);
  k_ebin<<<nchunk, 256, 0, stream>>>(ep, ne, nbuck, ghist, bbase, bins);
  k_bcount<<<nbuck, 256, 0, stream>>>(bbase, btot, bins, n, deg);
  k_blocksum<<<nblk, 256, 0, stream>>>(deg, n, bsum);
  k_scan_bsums<<<1, 256, 0, stream>>>(bsum, nblk, boff);
  k_scan_final<<<nblk, 256, 0, stream>>>(deg, n, boff, offsets, isd);
  k_bfill<<<nbuck, 256, 0, stream>>>(bbase, btot, bins, offsets, n, csr_dst);
  k_wsplit<<<8, 256, 0, stream>>>(W, Wh, Wl);
  k_gemm<<<(n + 127) / 128, 256, 0, stream>>>(X, Wh, Wl, b, T, Tb, n);
  k_gather<<<(n + 3) / 4, 256, 0, stream>>>(T, Tb, deg, isd, offsets, csr_dst,
                                            mm, var, gamma, beta, out, n);
}